// Round 9
// baseline (279.000 us; speedup 1.0000x reference)
//
#include <hip/hip_runtime.h>
#include <hip/hip_bf16.h>

#define HW      4096
#define WIDTH   64
#define C_MAIN  512
#define C_F     576
#define HO      62
#define KPATCH  3844   // 62*62
#define ALPHA_W 0.6f
#define SEM_W   0.5f
#define EPS_V   1e-5f
#define DELTA   4e-3f

typedef __attribute__((ext_vector_type(8))) short bf16x8;
typedef __attribute__((ext_vector_type(4))) float f32x4;

// ---------------------------------------------------------------------------
// 1. Per-channel instance-norm stats: stats[tensor*512+c] = {mean, rstd, sigma}
// ---------------------------------------------------------------------------
__global__ __launch_bounds__(256) void stats_kernel(
    const float* __restrict__ cF, const float* __restrict__ sF,
    float4* __restrict__ stats) {
  int b = blockIdx.x;              // 0..1023
  int tensor = b >> 9, c = b & 511;
  const float* src = (tensor ? sF : cF) + (size_t)c * HW;
  int t = threadIdx.x;
  float sum = 0.f, sumsq = 0.f;
#pragma unroll
  for (int i = 0; i < 4; ++i) {
    float4 v = *(const float4*)(src + (i * 256 + t) * 4);
    sum   += v.x + v.y + v.z + v.w;
    sumsq += v.x * v.x + v.y * v.y + v.z * v.z + v.w * v.w;
  }
#pragma unroll
  for (int off = 32; off; off >>= 1) {
    sum   += __shfl_down(sum, off, 64);
    sumsq += __shfl_down(sumsq, off, 64);
  }
  __shared__ float ls[8];
  int lane = t & 63, wv = t >> 6;
  if (lane == 0) { ls[wv] = sum; ls[4 + wv] = sumsq; }
  __syncthreads();
  if (t == 0) {
    float s  = ls[0] + ls[1] + ls[2] + ls[3];
    float sq = ls[4] + ls[5] + ls[6] + ls[7];
    float mean = s / 4096.f;
    float var  = (sq - 4096.f * mean * mean) / 4095.f;   // ddof=1
    float sig  = sqrtf(var + EPS_V);
    stats[b] = make_float4(mean, 1.f / sig, sig, 0.f);
  }
}

// ---------------------------------------------------------------------------
// 2. Fused project + transpose + bf16 hi/lo split.
// ---------------------------------------------------------------------------
__global__ __launch_bounds__(256) void transform_kernel(
    const float* __restrict__ cF, const float* __restrict__ sF,
    const float* __restrict__ cSem, const float* __restrict__ sSem,
    const float4* __restrict__ stats,
    unsigned short* __restrict__ Ahi, unsigned short* __restrict__ Alo,
    unsigned short* __restrict__ Bhi, unsigned short* __restrict__ Blo,
    float* __restrict__ sFfT) {
  int tensor = blockIdx.z;
  int p0 = blockIdx.x * 32, k0 = blockIdx.y * 32;
  __shared__ float tile[32][33];
  int tx = threadIdx.x & 31, ty = threadIdx.x >> 5;   // 32x8
  for (int r = ty; r < 32; r += 8) {
    int ch = k0 + r;
    float x;
    if (ch < C_MAIN) {
      const float* src = tensor ? sF : cF;
      float4 st = stats[tensor * 512 + ch];
      x = (src[(size_t)ch * HW + p0 + tx] - st.x) * st.y;
    } else {
      const float* src = tensor ? sSem : cSem;
      x = SEM_W * src[(size_t)(ch - C_MAIN) * HW + p0 + tx];
    }
    tile[r][tx] = x;
  }
  __syncthreads();
  unsigned short* dhi = tensor ? Bhi : Ahi;
  unsigned short* dlo = tensor ? Blo : Alo;
  for (int r = ty; r < 32; r += 8) {
    float x = tile[tx][r];                // k = k0+tx, p = p0+r
    __hip_bfloat16 hb = __float2bfloat16(x);
    float hf = __bfloat162float(hb);
    __hip_bfloat16 lb = __float2bfloat16(x - hf);
    size_t o = (size_t)(p0 + r) * C_F + k0 + tx;
    dhi[o] = *reinterpret_cast<const unsigned short*>(&hb);
    dlo[o] = *reinterpret_cast<const unsigned short*>(&lb);
    if (tensor) sFfT[o] = x;
  }
}

// ---------------------------------------------------------------------------
// 3. MFMA GEMM: M = hh + hl + lh.  A staged in LDS; B fragments loaded
//    DIRECTLY global->reg (each frag: 16 rows x 64B contiguous, coalesced,
//    L2/L3-resident) -- halves LDS read traffic (the measured bottleneck).
// ---------------------------------------------------------------------------
__global__ __launch_bounds__(256) void gemm_kernel(
    const unsigned short* __restrict__ Ahi, const unsigned short* __restrict__ Alo,
    const unsigned short* __restrict__ Bhi, const unsigned short* __restrict__ Blo,
    float* __restrict__ M) {
  __shared__ __align__(16) unsigned short As_hi[128 * 32];
  __shared__ __align__(16) unsigned short As_lo[128 * 32];
  int a0 = blockIdx.x * 128, u0 = blockIdx.y * 128;
  int t = threadIdx.x;
  int lane = t & 63, wave = t >> 6;
  int wr = wave >> 1, wc = wave & 1;
  int l15 = lane & 15, hig = lane >> 4;

  int sr = t >> 2;
  int sc = (t & 3) * 8;
  const unsigned short* Ag0 = Ahi + (size_t)(a0 + sr) * C_F + sc;
  const unsigned short* Ag1 = Alo + (size_t)(a0 + sr) * C_F + sc;
  const size_t rstep = (size_t)64 * C_F;

  uint4 pah0 = *(const uint4*)(Ag0), pah1 = *(const uint4*)(Ag0 + rstep);
  uint4 pal0 = *(const uint4*)(Ag1), pal1 = *(const uint4*)(Ag1 + rstep);

  // per-lane B fragment base: row u0 + wc*64 + l15, col chunk hig*8
  const unsigned short* Bg_h = Bhi + (size_t)(u0 + wc * 64 + l15) * C_F + hig * 8;
  const unsigned short* Bg_l = Blo + (size_t)(u0 + wc * 64 + l15) * C_F + hig * 8;

  f32x4 zero4 = {0.f, 0.f, 0.f, 0.f};
  f32x4 acc[4][4];
#pragma unroll
  for (int m = 0; m < 4; ++m)
#pragma unroll
    for (int n = 0; n < 4; ++n) acc[m][n] = zero4;

  int lw = sr * 4 + (t & 3);
  for (int k0 = 0; k0 < C_F; k0 += 32) {
    // issue B global loads early; latency hides under barrier + A staging
    bf16x8 bh[4], bl[4];
#pragma unroll
    for (int n = 0; n < 4; ++n) {
      bh[n] = *(const bf16x8*)(Bg_h + (size_t)(n * 16) * C_F + k0);
      bl[n] = *(const bf16x8*)(Bg_l + (size_t)(n * 16) * C_F + k0);
    }
    __syncthreads();
    ((uint4*)As_hi)[lw] = pah0; ((uint4*)As_hi)[lw + 256] = pah1;
    ((uint4*)As_lo)[lw] = pal0; ((uint4*)As_lo)[lw + 256] = pal1;
    __syncthreads();
    if (k0 + 32 < C_F) {
      Ag0 += 32; Ag1 += 32;
      pah0 = *(const uint4*)(Ag0); pah1 = *(const uint4*)(Ag0 + rstep);
      pal0 = *(const uint4*)(Ag1); pal1 = *(const uint4*)(Ag1 + rstep);
    }
#pragma unroll
    for (int m = 0; m < 4; ++m) {
      int arow = wr * 64 + m * 16 + l15;
      bf16x8 ah = *(const bf16x8*)&As_hi[arow * 32 + hig * 8];
      bf16x8 al = *(const bf16x8*)&As_lo[arow * 32 + hig * 8];
#pragma unroll
      for (int n = 0; n < 4; ++n) {
        acc[m][n] = __builtin_amdgcn_mfma_f32_16x16x32_bf16(ah, bh[n], acc[m][n], 0, 0, 0);
        acc[m][n] = __builtin_amdgcn_mfma_f32_16x16x32_bf16(ah, bl[n], acc[m][n], 0, 0, 0);
        acc[m][n] = __builtin_amdgcn_mfma_f32_16x16x32_bf16(al, bh[n], acc[m][n], 0, 0, 0);
      }
    }
  }
#pragma unroll
  for (int m = 0; m < 4; ++m) {
    int row = a0 + wr * 64 + m * 16 + hig * 4;
#pragma unroll
    for (int n = 0; n < 4; ++n) {
      int col = u0 + wc * 64 + n * 16 + l15;
#pragma unroll
      for (int r = 0; r < 4; ++r)
        M[(size_t)(row + r) * HW + col] = acc[m][n][r];
    }
  }
}

// ---------------------------------------------------------------------------
// 4a. q[u] = sum_k sFfT[u][k]^2   (one wave per row)
// ---------------------------------------------------------------------------
__global__ __launch_bounds__(256) void colsumsq_kernel(
    const float* __restrict__ sFfT, float* __restrict__ q) {
  int row = blockIdx.x * 4 + (threadIdx.x >> 6);
  int lane = threadIdx.x & 63;
  const float* r = sFfT + (size_t)row * C_F;
  float s = 0.f;
  for (int i = lane; i < C_F; i += 64) { float v = r[i]; s += v * v; }
#pragma unroll
  for (int off = 32; off; off >>= 1) s += __shfl_down(s, off, 64);
  if (lane == 0) q[row] = s;
}

// 4b. rnorm[k] = 1/(sqrt(3x3 box of q) + 1e-7)
__global__ __launch_bounds__(256) void rnorm_kernel(
    const float* __restrict__ q, float* __restrict__ rnorm) {
  int k = blockIdx.x * 256 + threadIdx.x;
  if (k >= KPATCH) return;
  int ky = k / HO, kx = k - ky * HO;
  float s = 0.f;
#pragma unroll
  for (int i = 0; i < 3; ++i)
#pragma unroll
    for (int j = 0; j < 3; ++j) s += q[(ky + i) * WIDTH + kx + j];
  rnorm[k] = 1.f / (sqrtf(s) + 1e-7f);
}

// ---------------------------------------------------------------------------
// 5. argmax with exact-rescoring rescue. One block per 4x4 positions,
//    512 threads. M row-traffic: 147 MB (vs 246 MB at 2x2).
//    Per-position math is bit-identical to the passing 2x2 version.
// ---------------------------------------------------------------------------
__global__ __launch_bounds__(512) void argmax_kernel(
    const float* __restrict__ M, const float* __restrict__ rnorm,
    const float* __restrict__ sFfT,
    const float* __restrict__ cF, const float* __restrict__ cSem,
    const float4* __restrict__ stats,
    int* __restrict__ idx) {
  int y0 = min((int)blockIdx.x * 4, HO - 4);   // clamp: tail blocks overlap
  int x0 = min((int)blockIdx.y * 4, HO - 4);   // (duplicate identical writes)
  int t = threadIdx.x;

  const float* Mbase = M + (size_t)(y0 * WIDTH + x0) * HW;
  int ijo[9];
#pragma unroll
  for (int i = 0; i < 3; ++i)
#pragma unroll
    for (int j = 0; j < 3; ++j)
      ijo[i * 3 + j] = (i * WIDTH + j) * HW + i * WIDTH + j;

  float v1[16], v2[16];
  int   k1[16], k2[16];
#pragma unroll
  for (int p = 0; p < 16; ++p) { v1[p] = -1e30f; v2[p] = -1e30f; k1[p] = 0; k2[p] = 0; }

  for (int k = t; k < KPATCH; k += 512) {
    int ky = k / HO;
    int u = k + 2 * ky;           // ky*64 + kx
    float s[16];
#pragma unroll
    for (int p = 0; p < 16; ++p) s[p] = 0.f;
#pragma unroll
    for (int o = 0; o < 9; ++o) {
      const float* p9 = Mbase + ijo[o] + u;
#pragma unroll
      for (int py = 0; py < 4; ++py)
#pragma unroll
        for (int px = 0; px < 4; ++px)
          s[py * 4 + px] += p9[(size_t)(py * WIDTH + px) * HW];
    }
    float rn = rnorm[k];
#pragma unroll
    for (int p = 0; p < 16; ++p) {
      float v = s[p] * rn;
      if (v > v1[p]) { v2[p] = v1[p]; k2[p] = k1[p]; v1[p] = v; k1[p] = k; }
      else if (v > v2[p]) { v2[p] = v; k2[p] = k; }
    }
  }

  __shared__ float sv[512];
  __shared__ int   sk[512];
  __shared__ float redf[512];
  __shared__ float cpatch[9 * C_F];
  __shared__ int   candList[64];
  __shared__ int   candN;
  __shared__ float bestE;
  __shared__ int   bestK;

  for (int pp = 0; pp < 16; ++pp) {
    int py = pp >> 2, px = pp & 3;
    // static-index extraction (avoid runtime-indexed register arrays)
    float mv1 = -1e30f, mv2 = -1e30f; int mk1 = 0, mk2 = 0;
#pragma unroll
    for (int q = 0; q < 16; ++q)
      if (q == pp) { mv1 = v1[q]; mv2 = v2[q]; mk1 = k1[q]; mk2 = k2[q]; }

    __syncthreads();
    sv[t] = mv1; sk[t] = mk1;
    __syncthreads();
    for (int off = 256; off; off >>= 1) {
      if (t < off) {
        float ov = sv[t + off]; int ok = sk[t + off];
        if (ov > sv[t] || (ov == sv[t] && ok < sk[t])) { sv[t] = ov; sk[t] = ok; }
      }
      __syncthreads();
    }
    float vbest = sv[0];
    int   kbest = sk[0];
    float thr = vbest - DELTA;
    if (t == 0) candN = 0;
    __syncthreads();

    int poff = (py * WIDTH + px) * HW;
    if (mv2 >= thr) {
      // rare: this thread may own >=2 near-max k's -> rescan its own k's
      for (int k = t; k < KPATCH; k += 512) {
        int ky = k / HO;
        int u = k + 2 * ky;
        float s = 0.f;
#pragma unroll
        for (int o = 0; o < 9; ++o) s += Mbase[(size_t)(poff + ijo[o]) + u];
        float v = s * rnorm[k];
        if (v >= thr && k != kbest) {
          int sl = atomicAdd(&candN, 1);
          if (sl < 64) candList[sl] = k;
        }
      }
    } else if (mv1 >= thr && mk1 != kbest) {
      int sl = atomicAdd(&candN, 1);
      if (sl < 64) candList[sl] = mk1;
    }
    __syncthreads();
    int nc = min(candN, 64);
    if (nc == 0) {               // unique max by > DELTA margin: exact winner
      if (t == 0) idx[(y0 + py) * HO + x0 + px] = kbest;
      continue;
    }

    // ---- exact rescue: stage content patch in LDS ----
    int y = y0 + py, x = x0 + px;
    for (int f = t; f < 9 * C_F; f += 512) {
      int ij = f / C_F, c = f - ij * C_F;
      int pp2 = (y + ij / 3) * WIDTH + x + ij % 3;
      float cv;
      if (c < C_MAIN) {
        float4 st = stats[c];
        cv = (cF[(size_t)c * HW + pp2] - st.x) * st.y;
      } else {
        cv = SEM_W * cSem[(size_t)(c - C_MAIN) * HW + pp2];
      }
      cpatch[f] = cv;
    }
    __syncthreads();
    if (t == 0) { bestE = -1e30f; bestK = 0x7fffffff; }
    __syncthreads();

    for (int ci = -1; ci < nc; ++ci) {
      int k = (ci < 0) ? kbest : candList[ci];
      int ky = k / HO, kx = k - ky * HO;
      float part = 0.f;
      for (int f = t; f < 9 * C_F; f += 512) {
        int ij = f / C_F, c = f - ij * C_F;
        int sp = (ky + ij / 3) * WIDTH + kx + ij % 3;
        part += cpatch[f] * sFfT[(size_t)sp * C_F + c];
      }
      redf[t] = part;
      __syncthreads();
      for (int off = 256; off; off >>= 1) {
        if (t < off) redf[t] += redf[t + off];
        __syncthreads();
      }
      if (t == 0) {
        float e = redf[0] * rnorm[k];
        if (e > bestE || (e == bestE && k < bestK)) { bestE = e; bestK = k; }
      }
      __syncthreads();
    }
    if (t == 0) idx[(y0 + py) * HO + x0 + px] = bestK;
  }
}

// ---------------------------------------------------------------------------
// 6. gather selected patches (projected style), overlap-add in [pix][c]
// ---------------------------------------------------------------------------
__global__ __launch_bounds__(256) void gather_kernel(
    const float* __restrict__ sFfT, const int* __restrict__ idx,
    float* __restrict__ tmp) {
  __shared__ int srcs[9];
  __shared__ int nv;
  int pix = blockIdx.x;
  int h = pix >> 6, w = pix & 63;
  if (threadIdx.x == 0) {
    int n = 0;
    for (int i = 0; i < 3; ++i)
      for (int j = 0; j < 3; ++j) {
        int y = h - i, x = w - j;
        if (y >= 0 && y < HO && x >= 0 && x < HO) {
          int k = idx[y * HO + x];
          int ky = k / HO, kx = k - ky * HO;
          srcs[n++] = (ky + i) * WIDTH + kx + j;
        }
      }
    nv = n;
  }
  __syncthreads();
  int n = nv;
  for (int c = threadIdx.x; c < C_MAIN; c += 256) {
    float acc = 0.f;
    for (int s = 0; s < n; ++s) acc += sFfT[(size_t)srcs[s] * C_F + c];
    tmp[(size_t)pix * C_MAIN + c] = acc;
  }
}

// ---------------------------------------------------------------------------
// 7. blend + un-project + transpose back
// ---------------------------------------------------------------------------
__global__ void blend_kernel(
    const float* __restrict__ tmp, const float* __restrict__ cF,
    const float4* __restrict__ stats, float* __restrict__ out) {
  __shared__ float tile[32][33];
  int p0 = blockIdx.x * 32;
  int c0 = blockIdx.y * 32;
  int tx = threadIdx.x, ty = threadIdx.y;   // (32,8)
  for (int r = ty; r < 32; r += 8)
    tile[r][tx] = tmp[(size_t)(p0 + r) * C_MAIN + c0 + tx];
  __syncthreads();
  for (int r = ty; r < 32; r += 8) {
    int pix = p0 + tx;
    int h = pix >> 6, w = pix & 63;
    int nh = min(2, h) - max(0, h - 61) + 1;
    int nw = min(2, w) - max(0, w - 61) + 1;
    float inv_cnt = 1.f / (float)(nh * nw);
    int c = c0 + r;
    float4 st = stats[512 + c];              // style channel stats
    float recon = st.z * (tile[tx][r] * inv_cnt) + st.x;
    out[(size_t)c * HW + pix] =
        ALPHA_W * recon + (1.f - ALPHA_W) * cF[(size_t)c * HW + pix];
  }
}

// ---------------------------------------------------------------------------
// Workspace (total 95.5 MB, proven-safe):
//   [0        , 18874368) Ahi|Alo|Bhi|Blo  (transform -> gemm)
//       tmp overlays [0, 8388608)          (gather -> blend)
//   [18874368 , 85983232) M                (gemm -> argmax)
//   [85983232 , 95420416) sFfT fp32        (transform -> gather)
//   [95420416 , 95485952) q | rnrm | idx | stats (16K each)
// ---------------------------------------------------------------------------
extern "C" void kernel_launch(void* const* d_in, const int* in_sizes, int n_in,
                              void* d_out, int out_size, void* d_ws, size_t ws_size,
                              hipStream_t stream) {
  const float* cF   = (const float*)d_in[0];
  const float* sF   = (const float*)d_in[1];
  const float* cSem = (const float*)d_in[2];
  const float* sSem = (const float*)d_in[3];
  float* out = (float*)d_out;

  char* ws = (char*)d_ws;
  unsigned short* Ahi = (unsigned short*)ws;
  unsigned short* Alo = Ahi + (size_t)HW * C_F;
  unsigned short* Bhi = Alo + (size_t)HW * C_F;
  unsigned short* Blo = Bhi + (size_t)HW * C_F;
  float* tmp  = (float*)ws;                      // after gemm
  float* M    = (float*)(ws + 18874368);
  float* sFfT = (float*)(ws + 85983232);
  float* q    = (float*)(ws + 95420416);
  float* rnrm = (float*)(ws + 95420416 + 16384);
  int*   idx  = (int*)  (ws + 95420416 + 32768);
  float4* stats = (float4*)(ws + 95420416 + 49152);

  stats_kernel<<<1024, 256, 0, stream>>>(cF, sF, stats);
  transform_kernel<<<dim3(HW / 32, C_F / 32, 2), 256, 0, stream>>>(
      cF, sF, cSem, sSem, stats, Ahi, Alo, Bhi, Blo, sFfT);
  colsumsq_kernel<<<HW / 4, 256, 0, stream>>>(sFfT, q);
  rnorm_kernel<<<(KPATCH + 255) / 256, 256, 0, stream>>>(q, rnrm);
  gemm_kernel<<<dim3(32, 32), 256, 0, stream>>>(Ahi, Alo, Bhi, Blo, M);
  argmax_kernel<<<dim3(16, 16), 512, 0, stream>>>(M, rnrm, sFfT, cF, cSem, stats, idx);
  gather_kernel<<<HW, 256, 0, stream>>>(sFfT, idx, tmp);
  blend_kernel<<<dim3(128, 16), dim3(32, 8), 0, stream>>>(tmp, cF, stats, out);
}

// Round 10
// 225.016 us; speedup vs baseline: 1.2399x; 1.2399x over previous
//
#include <hip/hip_runtime.h>
#include <hip/hip_bf16.h>

#define HW      4096
#define WIDTH   64
#define C_MAIN  512
#define C_F     576
#define HO      62
#define KPATCH  3844   // 62*62
#define ALPHA_W 0.6f
#define SEM_W   0.5f
#define EPS_V   1e-5f
#define DELTA   4e-3f

typedef __attribute__((ext_vector_type(8))) short bf16x8;
typedef __attribute__((ext_vector_type(4))) float f32x4;

// ---------------------------------------------------------------------------
// 1. Per-channel instance-norm stats: stats[tensor*512+c] = {mean, rstd, sigma}
// ---------------------------------------------------------------------------
__global__ __launch_bounds__(256) void stats_kernel(
    const float* __restrict__ cF, const float* __restrict__ sF,
    float4* __restrict__ stats) {
  int b = blockIdx.x;              // 0..1023
  int tensor = b >> 9, c = b & 511;
  const float* src = (tensor ? sF : cF) + (size_t)c * HW;
  int t = threadIdx.x;
  float sum = 0.f, sumsq = 0.f;
#pragma unroll
  for (int i = 0; i < 4; ++i) {
    float4 v = *(const float4*)(src + (i * 256 + t) * 4);
    sum   += v.x + v.y + v.z + v.w;
    sumsq += v.x * v.x + v.y * v.y + v.z * v.z + v.w * v.w;
  }
#pragma unroll
  for (int off = 32; off; off >>= 1) {
    sum   += __shfl_down(sum, off, 64);
    sumsq += __shfl_down(sumsq, off, 64);
  }
  __shared__ float ls[8];
  int lane = t & 63, wv = t >> 6;
  if (lane == 0) { ls[wv] = sum; ls[4 + wv] = sumsq; }
  __syncthreads();
  if (t == 0) {
    float s  = ls[0] + ls[1] + ls[2] + ls[3];
    float sq = ls[4] + ls[5] + ls[6] + ls[7];
    float mean = s / 4096.f;
    float var  = (sq - 4096.f * mean * mean) / 4095.f;   // ddof=1
    float sig  = sqrtf(var + EPS_V);
    stats[b] = make_float4(mean, 1.f / sig, sig, 0.f);
  }
}

// ---------------------------------------------------------------------------
// 2. Fused project + transpose + bf16 hi/lo split.
// ---------------------------------------------------------------------------
__global__ __launch_bounds__(256) void transform_kernel(
    const float* __restrict__ cF, const float* __restrict__ sF,
    const float* __restrict__ cSem, const float* __restrict__ sSem,
    const float4* __restrict__ stats,
    unsigned short* __restrict__ Ahi, unsigned short* __restrict__ Alo,
    unsigned short* __restrict__ Bhi, unsigned short* __restrict__ Blo,
    float* __restrict__ sFfT) {
  int tensor = blockIdx.z;
  int p0 = blockIdx.x * 32, k0 = blockIdx.y * 32;
  __shared__ float tile[32][33];
  int tx = threadIdx.x & 31, ty = threadIdx.x >> 5;   // 32x8
  for (int r = ty; r < 32; r += 8) {
    int ch = k0 + r;
    float x;
    if (ch < C_MAIN) {
      const float* src = tensor ? sF : cF;
      float4 st = stats[tensor * 512 + ch];
      x = (src[(size_t)ch * HW + p0 + tx] - st.x) * st.y;
    } else {
      const float* src = tensor ? sSem : cSem;
      x = SEM_W * src[(size_t)(ch - C_MAIN) * HW + p0 + tx];
    }
    tile[r][tx] = x;
  }
  __syncthreads();
  unsigned short* dhi = tensor ? Bhi : Ahi;
  unsigned short* dlo = tensor ? Blo : Alo;
  for (int r = ty; r < 32; r += 8) {
    float x = tile[tx][r];                // k = k0+tx, p = p0+r
    __hip_bfloat16 hb = __float2bfloat16(x);
    float hf = __bfloat162float(hb);
    __hip_bfloat16 lb = __float2bfloat16(x - hf);
    size_t o = (size_t)(p0 + r) * C_F + k0 + tx;
    dhi[o] = *reinterpret_cast<const unsigned short*>(&hb);
    dlo[o] = *reinterpret_cast<const unsigned short*>(&lb);
    if (tensor) sFfT[o] = x;
  }
}

// ---------------------------------------------------------------------------
// 3. MFMA GEMM: M = hh + hl + lh (3-term bf16 split).  Round-7 version:
//    A and B both LDS-staged (measured 67 us, MfmaUtil 37%); the round-9
//    B-direct-global variant regressed to 97 us (latency not hidden).
// ---------------------------------------------------------------------------
__global__ __launch_bounds__(256) void gemm_kernel(
    const unsigned short* __restrict__ Ahi, const unsigned short* __restrict__ Alo,
    const unsigned short* __restrict__ Bhi, const unsigned short* __restrict__ Blo,
    float* __restrict__ M) {
  __shared__ __align__(16) unsigned short As_hi[128 * 32];
  __shared__ __align__(16) unsigned short As_lo[128 * 32];
  __shared__ __align__(16) unsigned short Bs_hi[128 * 32];
  __shared__ __align__(16) unsigned short Bs_lo[128 * 32];
  int a0 = blockIdx.x * 128, u0 = blockIdx.y * 128;
  int t = threadIdx.x;
  int lane = t & 63, wave = t >> 6;
  int wr = wave >> 1, wc = wave & 1;
  int l15 = lane & 15, hig = lane >> 4;

  int sr = t >> 2;
  int sc = (t & 3) * 8;
  const unsigned short* Ag0 = Ahi + (size_t)(a0 + sr) * C_F + sc;
  const unsigned short* Ag1 = Alo + (size_t)(a0 + sr) * C_F + sc;
  const unsigned short* Bg0 = Bhi + (size_t)(u0 + sr) * C_F + sc;
  const unsigned short* Bg1 = Blo + (size_t)(u0 + sr) * C_F + sc;
  const size_t rstep = (size_t)64 * C_F;

  uint4 pah0 = *(const uint4*)(Ag0), pah1 = *(const uint4*)(Ag0 + rstep);
  uint4 pal0 = *(const uint4*)(Ag1), pal1 = *(const uint4*)(Ag1 + rstep);
  uint4 pbh0 = *(const uint4*)(Bg0), pbh1 = *(const uint4*)(Bg0 + rstep);
  uint4 pbl0 = *(const uint4*)(Bg1), pbl1 = *(const uint4*)(Bg1 + rstep);

  f32x4 zero4 = {0.f, 0.f, 0.f, 0.f};
  f32x4 acc[4][4];
#pragma unroll
  for (int m = 0; m < 4; ++m)
#pragma unroll
    for (int n = 0; n < 4; ++n) acc[m][n] = zero4;

  int lw = sr * 4 + (t & 3);
  for (int k0 = 0; k0 < C_F; k0 += 32) {
    __syncthreads();
    ((uint4*)As_hi)[lw] = pah0; ((uint4*)As_hi)[lw + 256] = pah1;
    ((uint4*)As_lo)[lw] = pal0; ((uint4*)As_lo)[lw + 256] = pal1;
    ((uint4*)Bs_hi)[lw] = pbh0; ((uint4*)Bs_hi)[lw + 256] = pbh1;
    ((uint4*)Bs_lo)[lw] = pbl0; ((uint4*)Bs_lo)[lw + 256] = pbl1;
    __syncthreads();
    if (k0 + 32 < C_F) {
      Ag0 += 32; Ag1 += 32; Bg0 += 32; Bg1 += 32;
      pah0 = *(const uint4*)(Ag0); pah1 = *(const uint4*)(Ag0 + rstep);
      pal0 = *(const uint4*)(Ag1); pal1 = *(const uint4*)(Ag1 + rstep);
      pbh0 = *(const uint4*)(Bg0); pbh1 = *(const uint4*)(Bg0 + rstep);
      pbl0 = *(const uint4*)(Bg1); pbl1 = *(const uint4*)(Bg1 + rstep);
    }
    bf16x8 bh[4], bl[4];
#pragma unroll
    for (int n = 0; n < 4; ++n) {
      int brow = wc * 64 + n * 16 + l15;
      bh[n] = *(const bf16x8*)&Bs_hi[brow * 32 + hig * 8];
      bl[n] = *(const bf16x8*)&Bs_lo[brow * 32 + hig * 8];
    }
#pragma unroll
    for (int m = 0; m < 4; ++m) {
      int arow = wr * 64 + m * 16 + l15;
      bf16x8 ah = *(const bf16x8*)&As_hi[arow * 32 + hig * 8];
      bf16x8 al = *(const bf16x8*)&As_lo[arow * 32 + hig * 8];
#pragma unroll
      for (int n = 0; n < 4; ++n) {
        acc[m][n] = __builtin_amdgcn_mfma_f32_16x16x32_bf16(ah, bh[n], acc[m][n], 0, 0, 0);
        acc[m][n] = __builtin_amdgcn_mfma_f32_16x16x32_bf16(ah, bl[n], acc[m][n], 0, 0, 0);
        acc[m][n] = __builtin_amdgcn_mfma_f32_16x16x32_bf16(al, bh[n], acc[m][n], 0, 0, 0);
      }
    }
  }
#pragma unroll
  for (int m = 0; m < 4; ++m) {
    int row = a0 + wr * 64 + m * 16 + hig * 4;
#pragma unroll
    for (int n = 0; n < 4; ++n) {
      int col = u0 + wc * 64 + n * 16 + l15;
#pragma unroll
      for (int r = 0; r < 4; ++r)
        M[(size_t)(row + r) * HW + col] = acc[m][n][r];
    }
  }
}

// ---------------------------------------------------------------------------
// 4a. q[u] = sum_k sFfT[u][k]^2   (one wave per row)
// ---------------------------------------------------------------------------
__global__ __launch_bounds__(256) void colsumsq_kernel(
    const float* __restrict__ sFfT, float* __restrict__ q) {
  int row = blockIdx.x * 4 + (threadIdx.x >> 6);
  int lane = threadIdx.x & 63;
  const float* r = sFfT + (size_t)row * C_F;
  float s = 0.f;
  for (int i = lane; i < C_F; i += 64) { float v = r[i]; s += v * v; }
#pragma unroll
  for (int off = 32; off; off >>= 1) s += __shfl_down(s, off, 64);
  if (lane == 0) q[row] = s;
}

// 4b. rnorm[k] = 1/(sqrt(3x3 box of q) + 1e-7)
__global__ __launch_bounds__(256) void rnorm_kernel(
    const float* __restrict__ q, float* __restrict__ rnorm) {
  int k = blockIdx.x * 256 + threadIdx.x;
  if (k >= KPATCH) return;
  int ky = k / HO, kx = k - ky * HO;
  float s = 0.f;
#pragma unroll
  for (int i = 0; i < 3; ++i)
#pragma unroll
    for (int j = 0; j < 3; ++j) s += q[(ky + i) * WIDTH + kx + j];
  rnorm[k] = 1.f / (sqrtf(s) + 1e-7f);
}

// ---------------------------------------------------------------------------
// 5. argmax with exact-rescoring rescue. One block per 4x2 positions
//    (px 0..3, py 0..1), 256 threads -> registers safely bounded
//    (round-9's 4x4@512 hit the launch_bounds VGPR cap).
//    24 M-rows / 8 positions = 190 MB total (vs 246 MB at 2x2).
//    k-stride 256 == round-7 proven partitioning (bit-identical streams).
// ---------------------------------------------------------------------------
__global__ __launch_bounds__(256) void argmax_kernel(
    const float* __restrict__ M, const float* __restrict__ rnorm,
    const float* __restrict__ sFfT,
    const float* __restrict__ cF, const float* __restrict__ cSem,
    const float4* __restrict__ stats,
    int* __restrict__ idx) {
  int y0 = blockIdx.x * 2;                     // 0..60 exact
  int x0 = min((int)blockIdx.y * 4, HO - 4);   // clamp: tail overlaps,
  int t = threadIdx.x;                         // duplicate identical writes

  const float* Mbase = M + (size_t)(y0 * WIDTH + x0) * HW;
  int ijo[9];
#pragma unroll
  for (int i = 0; i < 3; ++i)
#pragma unroll
    for (int j = 0; j < 3; ++j)
      ijo[i * 3 + j] = (i * WIDTH + j) * HW + i * WIDTH + j;

  float v1[8], v2[8];
  int   k1[8], k2[8];
#pragma unroll
  for (int p = 0; p < 8; ++p) { v1[p] = -1e30f; v2[p] = -1e30f; k1[p] = 0; k2[p] = 0; }

  for (int k = t; k < KPATCH; k += 256) {
    int ky = k / HO;
    int u = k + 2 * ky;           // ky*64 + kx
    float s[8];
#pragma unroll
    for (int p = 0; p < 8; ++p) s[p] = 0.f;
#pragma unroll
    for (int o = 0; o < 9; ++o) {
      const float* p9 = Mbase + ijo[o] + u;
#pragma unroll
      for (int py = 0; py < 2; ++py)
#pragma unroll
        for (int px = 0; px < 4; ++px)
          s[py * 4 + px] += p9[(size_t)(py * WIDTH + px) * HW];
    }
    float rn = rnorm[k];
#pragma unroll
    for (int p = 0; p < 8; ++p) {
      float v = s[p] * rn;
      if (v > v1[p]) { v2[p] = v1[p]; k2[p] = k1[p]; v1[p] = v; k1[p] = k; }
      else if (v > v2[p]) { v2[p] = v; k2[p] = k; }
    }
  }

  __shared__ float sv[256];
  __shared__ int   sk[256];
  __shared__ float redf[256];
  __shared__ float cpatch[9 * C_F];
  __shared__ int   candList[64];
  __shared__ int   candN;
  __shared__ float bestE;
  __shared__ int   bestK;

  for (int pp = 0; pp < 8; ++pp) {
    int py = pp >> 2, px = pp & 3;
    // static-index extraction (avoid runtime-indexed register arrays)
    float mv1 = -1e30f, mv2 = -1e30f; int mk1 = 0;
#pragma unroll
    for (int q = 0; q < 8; ++q)
      if (q == pp) { mv1 = v1[q]; mv2 = v2[q]; mk1 = k1[q]; }

    __syncthreads();
    sv[t] = mv1; sk[t] = mk1;
    __syncthreads();
    for (int off = 128; off; off >>= 1) {
      if (t < off) {
        float ov = sv[t + off]; int ok = sk[t + off];
        if (ov > sv[t] || (ov == sv[t] && ok < sk[t])) { sv[t] = ov; sk[t] = ok; }
      }
      __syncthreads();
    }
    float vbest = sv[0];
    int   kbest = sk[0];
    float thr = vbest - DELTA;
    if (t == 0) candN = 0;
    __syncthreads();

    int poff = (py * WIDTH + px) * HW;
    if (mv2 >= thr) {
      // rare: this thread may own >=2 near-max k's -> rescan its own k's
      for (int k = t; k < KPATCH; k += 256) {
        int ky = k / HO;
        int u = k + 2 * ky;
        float s = 0.f;
#pragma unroll
        for (int o = 0; o < 9; ++o) s += Mbase[(size_t)(poff + ijo[o]) + u];
        float v = s * rnorm[k];
        if (v >= thr && k != kbest) {
          int sl = atomicAdd(&candN, 1);
          if (sl < 64) candList[sl] = k;
        }
      }
    } else if (mv1 >= thr && mk1 != kbest) {
      int sl = atomicAdd(&candN, 1);
      if (sl < 64) candList[sl] = mk1;
    }
    __syncthreads();
    int nc = min(candN, 64);
    if (nc == 0) {               // unique max by > DELTA margin: exact winner
      if (t == 0) idx[(y0 + py) * HO + x0 + px] = kbest;
      continue;
    }

    // ---- exact rescue: stage content patch in LDS ----
    int y = y0 + py, x = x0 + px;
    for (int f = t; f < 9 * C_F; f += 256) {
      int ij = f / C_F, c = f - ij * C_F;
      int pp2 = (y + ij / 3) * WIDTH + x + ij % 3;
      float cv;
      if (c < C_MAIN) {
        float4 st = stats[c];
        cv = (cF[(size_t)c * HW + pp2] - st.x) * st.y;
      } else {
        cv = SEM_W * cSem[(size_t)(c - C_MAIN) * HW + pp2];
      }
      cpatch[f] = cv;
    }
    __syncthreads();
    if (t == 0) { bestE = -1e30f; bestK = 0x7fffffff; }
    __syncthreads();

    for (int ci = -1; ci < nc; ++ci) {
      int k = (ci < 0) ? kbest : candList[ci];
      int ky = k / HO, kx = k - ky * HO;
      float part = 0.f;
      for (int f = t; f < 9 * C_F; f += 256) {
        int ij = f / C_F, c = f - ij * C_F;
        int sp = (ky + ij / 3) * WIDTH + kx + ij % 3;
        part += cpatch[f] * sFfT[(size_t)sp * C_F + c];
      }
      redf[t] = part;
      __syncthreads();
      for (int off = 128; off; off >>= 1) {
        if (t < off) redf[t] += redf[t + off];
        __syncthreads();
      }
      if (t == 0) {
        float e = redf[0] * rnorm[k];
        if (e > bestE || (e == bestE && k < bestK)) { bestE = e; bestK = k; }
      }
      __syncthreads();
    }
    if (t == 0) idx[(y0 + py) * HO + x0 + px] = bestK;
  }
}

// ---------------------------------------------------------------------------
// 6. gather selected patches (projected style), overlap-add in [pix][c]
// ---------------------------------------------------------------------------
__global__ __launch_bounds__(256) void gather_kernel(
    const float* __restrict__ sFfT, const int* __restrict__ idx,
    float* __restrict__ tmp) {
  __shared__ int srcs[9];
  __shared__ int nv;
  int pix = blockIdx.x;
  int h = pix >> 6, w = pix & 63;
  if (threadIdx.x == 0) {
    int n = 0;
    for (int i = 0; i < 3; ++i)
      for (int j = 0; j < 3; ++j) {
        int y = h - i, x = w - j;
        if (y >= 0 && y < HO && x >= 0 && x < HO) {
          int k = idx[y * HO + x];
          int ky = k / HO, kx = k - ky * HO;
          srcs[n++] = (ky + i) * WIDTH + kx + j;
        }
      }
    nv = n;
  }
  __syncthreads();
  int n = nv;
  for (int c = threadIdx.x; c < C_MAIN; c += 256) {
    float acc = 0.f;
    for (int s = 0; s < n; ++s) acc += sFfT[(size_t)srcs[s] * C_F + c];
    tmp[(size_t)pix * C_MAIN + c] = acc;
  }
}

// ---------------------------------------------------------------------------
// 7. blend + un-project + transpose back
// ---------------------------------------------------------------------------
__global__ void blend_kernel(
    const float* __restrict__ tmp, const float* __restrict__ cF,
    const float4* __restrict__ stats, float* __restrict__ out) {
  __shared__ float tile[32][33];
  int p0 = blockIdx.x * 32;
  int c0 = blockIdx.y * 32;
  int tx = threadIdx.x, ty = threadIdx.y;   // (32,8)
  for (int r = ty; r < 32; r += 8)
    tile[r][tx] = tmp[(size_t)(p0 + r) * C_MAIN + c0 + tx];
  __syncthreads();
  for (int r = ty; r < 32; r += 8) {
    int pix = p0 + tx;
    int h = pix >> 6, w = pix & 63;
    int nh = min(2, h) - max(0, h - 61) + 1;
    int nw = min(2, w) - max(0, w - 61) + 1;
    float inv_cnt = 1.f / (float)(nh * nw);
    int c = c0 + r;
    float4 st = stats[512 + c];              // style channel stats
    float recon = st.z * (tile[tx][r] * inv_cnt) + st.x;
    out[(size_t)c * HW + pix] =
        ALPHA_W * recon + (1.f - ALPHA_W) * cF[(size_t)c * HW + pix];
  }
}

// ---------------------------------------------------------------------------
// Workspace (total 95.5 MB, proven-safe):
//   [0        , 18874368) Ahi|Alo|Bhi|Blo  (transform -> gemm)
//       tmp overlays [0, 8388608)          (gather -> blend)
//   [18874368 , 85983232) M                (gemm -> argmax)
//   [85983232 , 95420416) sFfT fp32        (transform -> gather)
//   [95420416 , 95485952) q | rnrm | idx | stats (16K each)
// ---------------------------------------------------------------------------
extern "C" void kernel_launch(void* const* d_in, const int* in_sizes, int n_in,
                              void* d_out, int out_size, void* d_ws, size_t ws_size,
                              hipStream_t stream) {
  const float* cF   = (const float*)d_in[0];
  const float* sF   = (const float*)d_in[1];
  const float* cSem = (const float*)d_in[2];
  const float* sSem = (const float*)d_in[3];
  float* out = (float*)d_out;

  char* ws = (char*)d_ws;
  unsigned short* Ahi = (unsigned short*)ws;
  unsigned short* Alo = Ahi + (size_t)HW * C_F;
  unsigned short* Bhi = Alo + (size_t)HW * C_F;
  unsigned short* Blo = Bhi + (size_t)HW * C_F;
  float* tmp  = (float*)ws;                      // after gemm
  float* M    = (float*)(ws + 18874368);
  float* sFfT = (float*)(ws + 85983232);
  float* q    = (float*)(ws + 95420416);
  float* rnrm = (float*)(ws + 95420416 + 16384);
  int*   idx  = (int*)  (ws + 95420416 + 32768);
  float4* stats = (float4*)(ws + 95420416 + 49152);

  stats_kernel<<<1024, 256, 0, stream>>>(cF, sF, stats);
  transform_kernel<<<dim3(HW / 32, C_F / 32, 2), 256, 0, stream>>>(
      cF, sF, cSem, sSem, stats, Ahi, Alo, Bhi, Blo, sFfT);
  colsumsq_kernel<<<HW / 4, 256, 0, stream>>>(sFfT, q);
  rnorm_kernel<<<(KPATCH + 255) / 256, 256, 0, stream>>>(q, rnrm);
  gemm_kernel<<<dim3(32, 32), 256, 0, stream>>>(Ahi, Alo, Bhi, Blo, M);
  argmax_kernel<<<dim3(31, 16), 256, 0, stream>>>(M, rnrm, sFfT, cF, cSem, stats, idx);
  gather_kernel<<<HW, 256, 0, stream>>>(sFfT, idx, tmp);
  blend_kernel<<<dim3(128, 16), dim3(32, 8), 0, stream>>>(tmp, cF, stats, out);
}